// Round 10
// baseline (71.934 us; speedup 1.0000x reference)
//
#include <hip/hip_runtime.h>

// ---- problem geometry ----
#define NN 160             // input dim
#define MM 152             // output dim (160-9+1)
#define TO 16              // output tile edge (y and x)
#define TI 24              // input tile edge = TO+8
#define XR 20              // xs row stride ([c][row][x], x inner), /4=5
#define XCH 488            // xs channel stride = 24*20+8 ; /4=122 == 2 mod 8 (Y-read balance)
#define YR 24              // ys y stride ([c][y][x], x inner): Z-read 2-way (free)
#define YCH 392            // ys channel stride = 16*24+8 ; /4=98 == 2 mod 8
#define ZC 19              // z-outputs per block (152 = 8*19)
#define PL 27              // planes per block = ZC+8
#define NSTEP (PL+2)       // 29 pipeline steps (X,Y,Z offsets 0,1,2)
#define NTX 10
#define NTILE 100
#define NBLK (NTILE*8)     // 800
#define INV_WIN (1.0f/729.0f)

__device__ __forceinline__ float cc_of(const float* s) {
    float cross = fmaf(-s[0] * s[1], INV_WIN, s[4]);
    float iv    = fmaf(-s[0] * s[0], INV_WIN, s[2]);
    float jv    = fmaf(-s[1] * s[1], INV_WIN, s[3]);
    return (cross * cross) / (iv * jv + 1e-6f);
}
__device__ __forceinline__ float4 f4add(float4 a, float4 b) {
    float4 r; r.x=a.x+b.x; r.y=a.y+b.y; r.z=a.z+b.z; r.w=a.w+b.w; return r;
}
__device__ __forceinline__ float4 f4sub(float4 a, float4 b) {
    float4 r; r.x=a.x-b.x; r.y=a.y-b.y; r.z=a.z-b.z; r.w=a.w-b.w; return r;
}

// load 12 consecutive floats (3 x float4) into a register array
#define LD12(dst, src) do {                                   \
    float4 a_ = *(const float4*)(src);                        \
    float4 b_ = *(const float4*)((src) + 4);                  \
    float4 c_ = *(const float4*)((src) + 8);                  \
    (dst)[0]=a_.x; (dst)[1]=a_.y; (dst)[2]=a_.z; (dst)[3]=a_.w; \
    (dst)[4]=b_.x; (dst)[5]=b_.y; (dst)[6]=b_.z; (dst)[7]=b_.w; \
    (dst)[8]=c_.x; (dst)[9]=c_.y; (dst)[10]=c_.z; (dst)[11]=c_.w; } while (0)

__global__ __launch_bounds__(256, 3) void lncc_fused(
    const float* __restrict__ I, const float* __restrict__ J,
    float* __restrict__ partial)
{
    // No raw-plane LDS: X reads global directly into registers.
    __shared__ __align__(16) float xsb[2][5 * XCH];   // x-sums [c][row][x]  19520 B
    __shared__ __align__(16) float ysb[2][5 * YCH];   // xy-sums [c][y][x]   15680 B
    __shared__ float red[4];

    const int tid  = threadIdx.x;
    const int orig = blockIdx.x;
    const int bid  = (orig & 7) * NTILE + (orig >> 3);  // XCD swizzle (800%8==0)
    const int tile = bid % NTILE;
    const int zc   = bid / NTILE;
    const int x0 = (tile % NTX) * TO;
    const int y0 = (tile / NTX) * TO;
    const int z0 = zc * ZC;

    const int yl = tid >> 4, xl = tid & 15;
    const bool valid = (x0 + xl < MM) && (y0 + yl < MM);

    // X mapping (tid < 96): (row 0..23, x-quad 0..3); global window 12 floats/img
    const int rowX = tid >> 2;
    const int xqX  = tid & 3;
    const int gyX  = min(y0 + rowX, NN - 1);       // clamps feed only invalid outputs
    const int gxX  = min(x0 + xqX * 4, NN - 12);
    const float* gIp = I + (size_t)gyX * NN + gxX;
    const float* gJp = J + (size_t)gyX * NN + gxX;

    // Y mapping (tid 128..167): 40 items = (ch, x-quad, y-half); float4 y-slide
    const int eY  = tid - 128;
    const int cY  = eY >> 3;
    const int xqY = (eY >> 1) & 3;
    const int yhY = eY & 1;

    // register-resident I/J windows, parity double-buffered (static idx via 18-unroll)
    float rI[2][12], rJ[2][12];
    if (tid < 96) {
        const float* pi = gIp + (size_t)z0 * (NN * NN);
        const float* pj = gJp + (size_t)z0 * (NN * NN);
        LD12(rI[0], pi);
        LD12(rJ[0], pj);
    }

    float ring[9][5];                              // z-window history (static idx only)
    float sz[5] = {0.f, 0.f, 0.f, 0.f, 0.f};
    float cc_acc = 0.f;

    for (int kb = 0; kb < 36; kb += 18) {          // kb in {0,18}: s&1 == ki&1 (static)
#pragma unroll
        for (int ki = 0; ki < 18; ++ki) {
            const int s = kb + ki;                 // pipeline step (block-uniform)
            if (s >= NSTEP) continue;
            const int p = ki & 1;                  // == s & 1

            // ---- X(s): registers -> 5-channel x-sums -> xsb[p]; prefetch s+1 ----
            if (s <= PL - 1 && tid < 96) {
                const float* bI = rI[p];
                const float* bJ = rJ[p];
#pragma unroll
                for (int c = 0; c < 5; ++c) {      // static: selects fold away
                    float m[12];
#pragma unroll
                    for (int t = 0; t < 12; ++t) {
                        float av = (c & 1) ? bJ[t] : bI[t];        // 0,2,4->I 1,3->J
                        float bv = (c < 2) ? 1.0f : ((c == 2) ? bI[t] : bJ[t]);
                        m[t] = av * bv;
                    }
                    float s0 = m[0]+m[1]+m[2]+m[3]+m[4]+m[5]+m[6]+m[7]+m[8];
                    float s1 = s0 + m[9]  - m[0];
                    float s2 = s1 + m[10] - m[1];
                    float s3 = s2 + m[11] - m[2];
                    float4 o; o.x = s0; o.y = s1; o.z = s2; o.w = s3;
                    *(float4*)&xsb[p][c * XCH + rowX * XR + xqX * 4] = o;
                }
                if (s <= PL - 2) {                 // prefetch plane s+1 into parity p^1
                    const float* pi = gIp + (size_t)(z0 + s + 1) * (NN * NN);
                    const float* pj = gJp + (size_t)(z0 + s + 1) * (NN * NN);
                    LD12(rI[p ^ 1], pi);
                    LD12(rJ[p ^ 1], pj);
                }
            }

            // ---- Y(s-1): xsb[p^1] -> ysb[p^1] (40 threads, float4 y-slide) ----
            if (s >= 1 && s <= PL && tid >= 128 && tid < 168) {
                const int q = p ^ 1;
                const float* xb = &xsb[q][cY * XCH + xqY * 4];
                float*       yb = &ysb[q][cY * YCH + xqY * 4];
                float4 w[9];
#pragma unroll
                for (int j = 0; j < 9; ++j)
                    w[j] = *(const float4*)&xb[(yhY * 8 + j) * XR];
                float4 o = f4add(f4add(f4add(f4add(w[0], w[1]), f4add(w[2], w[3])),
                                 f4add(f4add(w[4], w[5]), f4add(w[6], w[7]))), w[8]);
                *(float4*)&yb[(yhY * 8) * YR] = o;
#pragma unroll
                for (int t = 1; t < 8; ++t) {
                    float4 wn = *(const float4*)&xb[(yhY * 8 + t + 8) * XR];
                    o = f4add(o, f4sub(wn, w[t - 1]));
                    *(float4*)&yb[(yhY * 8 + t) * YR] = o;
                }
            }

            // ---- Z(s-2): ysb[p] sliding z-window + cc (2-way banks = free) ----
            if (s >= 2) {
                const int slot  = (ki + 7) % 9;    // (s-2)%9, static per unrolled copy
                const int slot2 = (ki + 8) % 9;    // (s-10)%9
                float v[5];
#pragma unroll
                for (int c = 0; c < 5; ++c) {
                    v[c] = ysb[p][c * YCH + yl * YR + xl];
                    sz[c] += v[c];
                    ring[slot][c] = v[c];
                }
                if (s >= 10) {                     // plane s-2 >= 8: emit output
                    cc_acc += valid ? cc_of(sz) : 0.f;
#pragma unroll
                    for (int c = 0; c < 5; ++c) sz[c] -= ring[slot2][c];
                }
            }

            __syncthreads();                       // single barrier per step
        }
    }

    // ---- block reduction (deterministic) ----
    for (int off = 32; off > 0; off >>= 1)
        cc_acc += __shfl_down(cc_acc, off, 64);
    if ((tid & 63) == 0) red[tid >> 6] = cc_acc;
    __syncthreads();
    if (tid == 0) partial[orig] = red[0] + red[1] + red[2] + red[3];
}

// ---- final deterministic reduction over 800 partials ----
__global__ __launch_bounds__(256) void lncc_final(
    const float* __restrict__ partial, float* __restrict__ out)
{
    double s = 0.0;
    for (int i = threadIdx.x; i < NBLK; i += 256)
        s += (double)partial[i];
    for (int off = 32; off > 0; off >>= 1)
        s += __shfl_down(s, off, 64);
    __shared__ double red[4];
    const int lane = threadIdx.x & 63, wid = threadIdx.x >> 6;
    if (lane == 0) red[wid] = s;
    __syncthreads();
    if (threadIdx.x == 0) {
        double tot = red[0] + red[1] + red[2] + red[3];
        out[0] = (float)(1.0 - tot / ((double)MM * MM * MM));
    }
}

extern "C" void kernel_launch(void* const* d_in, const int* in_sizes, int n_in,
                              void* d_out, int out_size, void* d_ws, size_t ws_size,
                              hipStream_t stream) {
    const float* I = (const float*)d_in[0];
    const float* J = (const float*)d_in[1];
    // d_in[2]: all-ones 9x9x9 filter, folded into the box-sum algebra.

    float* partial = (float*)d_ws;             // NBLK floats

    lncc_fused<<<NBLK, 256, 0, stream>>>(I, J, partial);
    lncc_final<<<1,    256, 0, stream>>>(partial, (float*)d_out);
    (void)in_sizes; (void)n_in; (void)out_size; (void)ws_size;
}

// Round 11
// 38.674 us; speedup vs baseline: 1.8600x; 1.8600x over previous
//
#include <hip/hip_runtime.h>

// ---- problem geometry ----
#define NN 160             // input dim
#define MM 152             // output dim (160-9+1)
#define TO 16              // output tile edge (y and x)
#define TI 24              // input tile edge = TO+8
#define PSTR 24            // Pld row stride (floats), 16B-aligned
#define PCH  (TI*PSTR)     // 576: Pld image stride (uniform per inst -> no conflict effect)
#define XROW 28            // xs x-dim stride (row dim inner); 112q%32=16q -> 2-way stores
#define XCH  (TO*XROW)     // 448: xs channel stride
#define YROW 20            // ys x-dim stride (y dim inner); 20x%32 spreads 8 quads
#define YCH  (TO*YROW)     // 320: ys channel stride
#define ZC 19              // z-outputs per block (152 = 8*19)
#define PL (ZC+8)          // 27 input planes per block
#define KMAX (PL+2)        // 29: pipeline steps 0..29
#define NZ 8
#define NTX 10
#define NTILE 100
#define NBLK (NTILE*8)     // 800
#define INV_WIN (1.0f/729.0f)

// Hot-loop barrier: order LDS (lgkmcnt) across threads but leave the commit
// wave's prefetch global loads (vmcnt) outstanding across the barrier — their
// only consumer is the issuing thread's ds_write next step (compiler inserts
// the vmcnt wait there via register dependency). __syncthreads() would drain
// vmcnt(0) every step and stall all 4 waves on HBM/L2 latency.
#define STEP_BARRIER() asm volatile("s_waitcnt lgkmcnt(0)\n\ts_barrier" ::: "memory")

__device__ __forceinline__ float cc_of(const float* s) {
    float cross = fmaf(-s[0] * s[1], INV_WIN, s[4]);
    float iv    = fmaf(-s[0] * s[0], INV_WIN, s[2]);
    float jv    = fmaf(-s[1] * s[1], INV_WIN, s[3]);
    return (cross * cross) / (iv * jv + 1e-6f);
}

__global__ __launch_bounds__(256, 4) void lncc_fused(
    const float* __restrict__ I, const float* __restrict__ J,
    float* __restrict__ partial)
{
    // One barrier per pipeline step: ALL buffers parity-double-buffered.
    __shared__ float Pld[2][2 * PCH];     // [parity][I|J plane tile]   9216 B
    __shared__ float xsb[2][5 * XCH];     // x-sums [c][x][row], dbuf  17920 B
    __shared__ float ysb[2][5 * YCH];     // xy-sums [c][x][y], dbuf   12800 B
    __shared__ float red[4];              //                            total 39952 B

    const int tid  = threadIdx.x;
    const int orig = blockIdx.x;
    const int bid  = (orig & 7) * NTILE + (orig >> 3);  // XCD-chunk swizzle (800%8==0)
    const int tile = bid % NTILE;
    const int zc   = bid / NTILE;
    const int x0 = (tile % NTX) * TO;
    const int y0 = (tile / NTX) * TO;
    const int z0 = zc * ZC;

    const int yl = tid >> 4, xl = tid & 15;
    const bool valid = (x0 + xl < MM) && (y0 + yl < MM);

    // loader mapping (tid < 144): 24 rows x 6 quads, one float4 per image
    const int lrow = tid / 6;
    const int lq   = tid - 6 * lrow;
    const int gy   = min(y0 + lrow, NN - 1);   // clamps only feed invalid outputs
    const int gx   = min(x0 + lq * 4, NN - 4);
    const size_t pbase = (size_t)gy * NN + gx;

    // X mapping (tid < 96): (row, x-quad); all 5 channels per thread
    const int rowX = tid >> 2;
    const int xbX  = (tid & 3) * 4;

    // Y mapping (tid 96..175): 80 items = (ch, x); full 24-row column per thread
    const int eY = tid - 96;
    const int cY = eY >> 4;
    const int xY = eY & 15;

    float4 pI, pJ;                             // prefetch registers
    if (tid < 144) {
        size_t a = (size_t)z0 * (NN * NN) + pbase;
        pI = *(const float4*)(I + a);
        pJ = *(const float4*)(J + a);
    }

    float ring[9][5];                          // z-window history (static idx only)
    float sz[5] = {0.f, 0.f, 0.f, 0.f, 0.f};
    float cc_acc = 0.f;

    for (int kb = 0; kb <= KMAX; kb += 9) {
#pragma unroll
        for (int ki = 0; ki < 9; ++ki) {
            const int k = kb + ki;             // pipeline step (block-uniform)
            if (k > KMAX) continue;

            // ---- commit(k) -> Pld[k&1], prefetch(k+1) (issue global loads first) ----
            if (k <= PL - 1 && tid < 144) {
                float* P = &Pld[k & 1][0];
                *(float4*)&P[lrow * PSTR + lq * 4]       = pI;
                *(float4*)&P[PCH + lrow * PSTR + lq * 4] = pJ;
                if (k <= PL - 2) {
                    size_t adr = (size_t)(z0 + k + 1) * (NN * NN) + pbase;
                    pI = *(const float4*)(I + adr);
                    pJ = *(const float4*)(J + adr);
                }
            }

            // ---- X(k-1): Pld[(k-1)&1] -> xsb[(k-1)&1] ----
            if (k >= 1 && k <= PL && tid < 96) {
                const int b = (k - 1) & 1;
                const float* P = &Pld[b][0];
                const float4* Ir = (const float4*)&P[rowX * PSTR + xbX];
                const float4* Jr = (const float4*)&P[PCH + rowX * PSTR + xbX];
                float4 i0 = Ir[0], i1 = Ir[1], i2 = Ir[2];
                float4 j0 = Jr[0], j1 = Jr[1], j2 = Jr[2];
                float iv[12], jv[12];
                iv[0]=i0.x; iv[1]=i0.y; iv[2]=i0.z; iv[3]=i0.w;
                iv[4]=i1.x; iv[5]=i1.y; iv[6]=i1.z; iv[7]=i1.w;
                iv[8]=i2.x; iv[9]=i2.y; iv[10]=i2.z; iv[11]=i2.w;
                jv[0]=j0.x; jv[1]=j0.y; jv[2]=j0.z; jv[3]=j0.w;
                jv[4]=j1.x; jv[5]=j1.y; jv[6]=j1.z; jv[7]=j1.w;
                jv[8]=j2.x; jv[9]=j2.y; jv[10]=j2.z; jv[11]=j2.w;
#pragma unroll
                for (int c = 0; c < 5; ++c) {   // static unroll: selects fold away
                    float m[12];
#pragma unroll
                    for (int t = 0; t < 12; ++t) {
                        float av = (c & 1) ? jv[t] : iv[t];        // 0,2,4->I 1,3->J
                        float bv = (c < 2) ? 1.0f : ((c == 2) ? iv[t] : jv[t]);
                        m[t] = av * bv;
                    }
                    float s = m[0]+m[1]+m[2]+m[3]+m[4]+m[5]+m[6]+m[7]+m[8];
                    float* W = &xsb[b][c * XCH + rowX];
                    W[xbX * XROW] = s;
#pragma unroll
                    for (int t = 1; t < 4; ++t) {
                        s += m[t + 8] - m[t - 1];
                        W[(xbX + t) * XROW] = s;
                    }
                }
            }

            // ---- Y(k-2): xsb[(k-2)&1] -> ysb[(k-2)&1] ----
            if (k >= 2 && k <= PL + 1 && tid >= 96 && tid < 176) {
                const int b = (k - 2) & 1;
                const float4* R = (const float4*)&xsb[b][cY * XCH + xY * XROW];
                float4 w0 = R[0], w1 = R[1], w2 = R[2], w3 = R[3], w4 = R[4], w5 = R[5];
                float m[24];
                m[0]=w0.x;  m[1]=w0.y;  m[2]=w0.z;  m[3]=w0.w;
                m[4]=w1.x;  m[5]=w1.y;  m[6]=w1.z;  m[7]=w1.w;
                m[8]=w2.x;  m[9]=w2.y;  m[10]=w2.z; m[11]=w2.w;
                m[12]=w3.x; m[13]=w3.y; m[14]=w3.z; m[15]=w3.w;
                m[16]=w4.x; m[17]=w4.y; m[18]=w4.z; m[19]=w4.w;
                m[20]=w5.x; m[21]=w5.y; m[22]=w5.z; m[23]=w5.w;
                float o[16];
                float s = m[0]+m[1]+m[2]+m[3]+m[4]+m[5]+m[6]+m[7]+m[8];
                o[0] = s;
#pragma unroll
                for (int t = 1; t < 16; ++t) {
                    s += m[t + 8] - m[t - 1];
                    o[t] = s;
                }
                float4* Wv = (float4*)&ysb[b][cY * YCH + xY * YROW];
                float4 oa = {o[0],  o[1],  o[2],  o[3]};
                float4 ob = {o[4],  o[5],  o[6],  o[7]};
                float4 oc = {o[8],  o[9],  o[10], o[11]};
                float4 od = {o[12], o[13], o[14], o[15]};
                Wv[0] = oa; Wv[1] = ob; Wv[2] = oc; Wv[3] = od;
            }

            // ---- Z(k-3): ysb[(k-3)&1] sliding z-window + cc ----
            if (k >= 3) {
                const int b = (k - 3) & 1;
                const int slot  = (ki + 6) % 9;   // (k-3)%9, static per unrolled copy
                const int slot2 = (ki + 7) % 9;   // (k-3-8)%9
                float v[5];
#pragma unroll
                for (int c = 0; c < 5; ++c) {
                    v[c] = ysb[b][c * YCH + xl * YROW + yl];
                    sz[c] += v[c];
                    ring[slot][c] = v[c];
                }
                if (k >= 11) {                    // pz = k-3 >= 8: emit output
                    cc_acc += valid ? cc_of(sz) : 0.f;
#pragma unroll
                    for (int c = 0; c < 5; ++c) sz[c] -= ring[slot2][c];
                }
            }

            STEP_BARRIER();                       // lgkmcnt(0)+s_barrier, vmcnt left open
        }
    }

    // ---- block reduction (deterministic) ----
    for (int off = 32; off > 0; off >>= 1)
        cc_acc += __shfl_down(cc_acc, off, 64);
    if ((tid & 63) == 0) red[tid >> 6] = cc_acc;
    __syncthreads();
    if (tid == 0) partial[orig] = red[0] + red[1] + red[2] + red[3];
}

// ---- final deterministic reduction over 800 partials ----
__global__ __launch_bounds__(256) void lncc_final(
    const float* __restrict__ partial, float* __restrict__ out)
{
    double s = 0.0;
    for (int i = threadIdx.x; i < NBLK; i += 256)
        s += (double)partial[i];
    for (int off = 32; off > 0; off >>= 1)
        s += __shfl_down(s, off, 64);
    __shared__ double red[4];
    const int lane = threadIdx.x & 63, wid = threadIdx.x >> 6;
    if (lane == 0) red[wid] = s;
    __syncthreads();
    if (threadIdx.x == 0) {
        double tot = red[0] + red[1] + red[2] + red[3];
        out[0] = (float)(1.0 - tot / ((double)MM * MM * MM));
    }
}

extern "C" void kernel_launch(void* const* d_in, const int* in_sizes, int n_in,
                              void* d_out, int out_size, void* d_ws, size_t ws_size,
                              hipStream_t stream) {
    const float* I = (const float*)d_in[0];
    const float* J = (const float*)d_in[1];
    // d_in[2]: all-ones 9x9x9 filter, folded into the box-sum algebra.

    float* partial = (float*)d_ws;             // NBLK floats

    lncc_fused<<<NBLK, 256, 0, stream>>>(I, J, partial);
    lncc_final<<<1,    256, 0, stream>>>(partial, (float*)d_out);
    (void)in_sizes; (void)n_in; (void)out_size; (void)ws_size;
}

// Round 12
// 34.798 us; speedup vs baseline: 2.0672x; 1.1114x over previous
//
#include <hip/hip_runtime.h>

// ---- problem geometry: tiles 8(x) x 32(y) x 19(z) ----
#define NN 160             // input dim
#define MM 152             // output dim (160-9+1)
#define TOX 8              // output tile x (19*8 = 152 exact, no x waste)
#define TOY 32             // output tile y
#define TIX 16             // input tile x
#define TIY 40             // input tile y
#define PS  20             // Pld row stride (16 floats + 4 pad)
#define PCH (TIY*PS)       // 800 floats per image
#define XST 44             // xs x-stride ([c][x][row], row inner: 40 + 4 pad)
#define XCH (TOX*XST)      // 352
#define YST 36             // ys x-stride ([c][x][y], y inner: 32 + 4 pad)
#define YCH (TOX*YST)      // 288
#define ZC 19              // z-outputs per block (152 = 8*19)
#define PL 27              // planes per block = ZC+8
#define KMAX 29            // pipeline steps 0..29 (X,Y,Z lag 1,2,3)
#define NTX 19
#define NTILE 95           // 19 x 5 tiles
#define NBLK (NTILE*8)     // 760 blocks = 2.97/CU (nearly balanced)
#define INV_WIN (1.0f/729.0f)

// lgkmcnt-only barrier: LDS ordering across threads; commit's prefetch global
// loads stay outstanding (their only consumer is the issuing thread's ds_write
// next step; compiler inserts the vmcnt wait there via register dependency).
#define STEP_BARRIER() asm volatile("s_waitcnt lgkmcnt(0)\n\ts_barrier" ::: "memory")

__device__ __forceinline__ float cc_of(const float* s) {
    float cross = fmaf(-s[0] * s[1], INV_WIN, s[4]);
    float iv    = fmaf(-s[0] * s[0], INV_WIN, s[2]);
    float jv    = fmaf(-s[1] * s[1], INV_WIN, s[3]);
    return (cross * cross) / (iv * jv + 1e-6f);
}

__global__ __launch_bounds__(256, 4) void lncc_fused(
    const float* __restrict__ I, const float* __restrict__ J,
    float* __restrict__ partial)
{
    __shared__ float Pld[2][2 * PCH];     // [parity][img][row][x]   12800 B
    __shared__ float xsb[2][5 * XCH];     // x-sums [c][x][row]      14080 B
    __shared__ float ysb[2][5 * YCH];     // xy-sums [c][x][y]       11520 B
    __shared__ float red[4];              //                   total 38416 B

    const int tid  = threadIdx.x;
    const int orig = blockIdx.x;
    const int bid  = (orig & 7) * NTILE + (orig >> 3);  // XCD swizzle (760 = 8*95)
    const int tile = bid % NTILE;
    const int zc   = bid / NTILE;
    const int x0 = (tile % NTX) * TOX;
    const int y0 = (tile / NTX) * TOY;
    const int z0 = zc * ZC;

    // Z mapping: one thread per output column (8x32 = 256, dense)
    const int yl = tid >> 3, xl = tid & 7;
    const bool valid = (y0 + yl < MM);        // x always valid (152 = 19*8)

    // X mapping (tid < 80): (row 0..39, half 0..1); 12-float window, 5 channels
    const int rowX = tid >> 1;
    const int qX   = tid & 1;

    // commit mapping (tid 80..159): 2 quad-items of 160 (row = i>>2, q = i&3)
    const int ce = tid - 80;
    const int r0 = ce >> 2,        q0 = ce & 3;          // rows 0..19
    const int r1 = (ce + 80) >> 2, q1 = (ce + 80) & 3;   // rows 20..39
    const size_t gb0 = (size_t)min(y0 + r0, NN - 1) * NN + (x0 + q0 * 4);
    const size_t gb1 = (size_t)min(y0 + r1, NN - 1) * NN + (x0 + q1 * 4);

    // Y mapping (tid 176..255): (c 0..4, x 0..7, yhalf 0..1)
    const int eY  = tid - 176;
    const int cY  = eY >> 4;
    const int xY  = (eY >> 1) & 7;
    const int yhY = eY & 1;

    float4 pI0, pJ0, pI1, pJ1;                 // prefetch registers (commit wave)
    if (tid >= 80 && tid < 160) {
        const size_t zb = (size_t)z0 * (NN * NN);
        pI0 = *(const float4*)(I + zb + gb0);
        pJ0 = *(const float4*)(J + zb + gb0);
        pI1 = *(const float4*)(I + zb + gb1);
        pJ1 = *(const float4*)(J + zb + gb1);
    }

    float ring[9][5];                          // z-window history (static idx only)
    float sz[5] = {0.f, 0.f, 0.f, 0.f, 0.f};
    float cc_acc = 0.f;

    for (int kb = 0; kb <= KMAX; kb += 9) {
#pragma unroll
        for (int ki = 0; ki < 9; ++ki) {
            const int k = kb + ki;             // pipeline step (block-uniform)
            if (k > KMAX) continue;

            // ---- commit(k) -> Pld[k&1]; prefetch plane k+1 ----
            if (k <= PL - 1 && tid >= 80 && tid < 160) {
                float* P = &Pld[k & 1][0];
                *(float4*)&P[r0 * PS + q0 * 4]       = pI0;
                *(float4*)&P[PCH + r0 * PS + q0 * 4] = pJ0;
                *(float4*)&P[r1 * PS + q1 * 4]       = pI1;
                *(float4*)&P[PCH + r1 * PS + q1 * 4] = pJ1;
                if (k <= PL - 2) {
                    const size_t zb = (size_t)(z0 + k + 1) * (NN * NN);
                    pI0 = *(const float4*)(I + zb + gb0);
                    pJ0 = *(const float4*)(J + zb + gb0);
                    pI1 = *(const float4*)(I + zb + gb1);
                    pJ1 = *(const float4*)(J + zb + gb1);
                }
            }

            // ---- X(k-1): Pld[(k-1)&1] -> xsb[(k-1)&1] (transposed b32 stores) ----
            if (k >= 1 && k <= PL && tid < 80) {
                const int b = (k - 1) & 1;
                const float* P = &Pld[b][0];
                const float4* Ir = (const float4*)&P[rowX * PS + qX * 4];
                const float4* Jr = (const float4*)&P[PCH + rowX * PS + qX * 4];
                float4 i0 = Ir[0], i1 = Ir[1], i2 = Ir[2];
                float4 j0 = Jr[0], j1 = Jr[1], j2 = Jr[2];
                float iv[12], jv[12];
                iv[0]=i0.x; iv[1]=i0.y; iv[2]=i0.z; iv[3]=i0.w;
                iv[4]=i1.x; iv[5]=i1.y; iv[6]=i1.z; iv[7]=i1.w;
                iv[8]=i2.x; iv[9]=i2.y; iv[10]=i2.z; iv[11]=i2.w;
                jv[0]=j0.x; jv[1]=j0.y; jv[2]=j0.z; jv[3]=j0.w;
                jv[4]=j1.x; jv[5]=j1.y; jv[6]=j1.z; jv[7]=j1.w;
                jv[8]=j2.x; jv[9]=j2.y; jv[10]=j2.z; jv[11]=j2.w;
#pragma unroll
                for (int c = 0; c < 5; ++c) {   // static unroll: selects fold away
                    float m[12];
#pragma unroll
                    for (int t = 0; t < 12; ++t) {
                        float av = (c & 1) ? jv[t] : iv[t];        // 0,2,4->I 1,3->J
                        float bv = (c < 2) ? 1.0f : ((c == 2) ? iv[t] : jv[t]);
                        m[t] = av * bv;
                    }
                    float s = m[0]+m[1]+m[2]+m[3]+m[4]+m[5]+m[6]+m[7]+m[8];
                    float* W = &xsb[b][c * XCH + rowX];
                    W[(qX * 4) * XST] = s;
#pragma unroll
                    for (int t = 1; t < 4; ++t) {
                        s += m[t + 8] - m[t - 1];
                        W[(qX * 4 + t) * XST] = s;
                    }
                }
            }

            // ---- Y(k-2): xsb[(k-2)&1] -> ysb[(k-2)&1] (b128 in, b128 out) ----
            if (k >= 2 && k <= PL + 1 && tid >= 176) {
                const int b = (k - 2) & 1;
                const float* xb = &xsb[b][cY * XCH + xY * XST + yhY * 16];
                float4 w0 = ((const float4*)xb)[0], w1 = ((const float4*)xb)[1],
                       w2 = ((const float4*)xb)[2], w3 = ((const float4*)xb)[3],
                       w4 = ((const float4*)xb)[4], w5 = ((const float4*)xb)[5];
                float m[24];
                m[0]=w0.x;  m[1]=w0.y;  m[2]=w0.z;  m[3]=w0.w;
                m[4]=w1.x;  m[5]=w1.y;  m[6]=w1.z;  m[7]=w1.w;
                m[8]=w2.x;  m[9]=w2.y;  m[10]=w2.z; m[11]=w2.w;
                m[12]=w3.x; m[13]=w3.y; m[14]=w3.z; m[15]=w3.w;
                m[16]=w4.x; m[17]=w4.y; m[18]=w4.z; m[19]=w4.w;
                m[20]=w5.x; m[21]=w5.y; m[22]=w5.z; m[23]=w5.w;
                float o[16];
                float s = m[0]+m[1]+m[2]+m[3]+m[4]+m[5]+m[6]+m[7]+m[8];
                o[0] = s;
#pragma unroll
                for (int t = 1; t < 16; ++t) {
                    s += m[t + 8] - m[t - 1];
                    o[t] = s;
                }
                float* yb = &ysb[b][cY * YCH + xY * YST + yhY * 16];
                float4 oa = {o[0],  o[1],  o[2],  o[3]};
                float4 ob = {o[4],  o[5],  o[6],  o[7]};
                float4 oc = {o[8],  o[9],  o[10], o[11]};
                float4 od = {o[12], o[13], o[14], o[15]};
                ((float4*)yb)[0] = oa; ((float4*)yb)[1] = ob;
                ((float4*)yb)[2] = oc; ((float4*)yb)[3] = od;
            }

            // ---- Z(k-3): ysb[(k-3)&1] sliding z-window + cc (2-way = free) ----
            if (k >= 3) {
                const int b = (k - 3) & 1;
                const int slot  = (ki + 6) % 9;   // (k-3)%9, static per unrolled copy
                const int slot2 = (ki + 7) % 9;   // (k-3-8)%9
                float v[5];
#pragma unroll
                for (int c = 0; c < 5; ++c) {
                    v[c] = ysb[b][c * YCH + xl * YST + yl];
                    sz[c] += v[c];
                    ring[slot][c] = v[c];
                }
                if (k >= 11) {                    // plane k-3 >= 8: emit output
                    cc_acc += valid ? cc_of(sz) : 0.f;
#pragma unroll
                    for (int c = 0; c < 5; ++c) sz[c] -= ring[slot2][c];
                }
            }

            STEP_BARRIER();                       // lgkmcnt(0)+s_barrier, vmcnt open
        }
    }

    // ---- block reduction (deterministic) ----
    for (int off = 32; off > 0; off >>= 1)
        cc_acc += __shfl_down(cc_acc, off, 64);
    if ((tid & 63) == 0) red[tid >> 6] = cc_acc;
    __syncthreads();
    if (tid == 0) partial[orig] = red[0] + red[1] + red[2] + red[3];
}

// ---- final deterministic reduction over 760 partials ----
__global__ __launch_bounds__(256) void lncc_final(
    const float* __restrict__ partial, float* __restrict__ out)
{
    double s = 0.0;
    for (int i = threadIdx.x; i < NBLK; i += 256)
        s += (double)partial[i];
    for (int off = 32; off > 0; off >>= 1)
        s += __shfl_down(s, off, 64);
    __shared__ double red[4];
    const int lane = threadIdx.x & 63, wid = threadIdx.x >> 6;
    if (lane == 0) red[wid] = s;
    __syncthreads();
    if (threadIdx.x == 0) {
        double tot = red[0] + red[1] + red[2] + red[3];
        out[0] = (float)(1.0 - tot / ((double)MM * MM * MM));
    }
}

extern "C" void kernel_launch(void* const* d_in, const int* in_sizes, int n_in,
                              void* d_out, int out_size, void* d_ws, size_t ws_size,
                              hipStream_t stream) {
    const float* I = (const float*)d_in[0];
    const float* J = (const float*)d_in[1];
    // d_in[2]: all-ones 9x9x9 filter, folded into the box-sum algebra.

    float* partial = (float*)d_ws;             // NBLK floats

    lncc_fused<<<NBLK, 256, 0, stream>>>(I, J, partial);
    lncc_final<<<1,    256, 0, stream>>>(partial, (float*)d_out);
    (void)in_sizes; (void)n_in; (void)out_size; (void)ws_size;
}